// Round 1
// baseline (1135.983 us; speedup 1.0000x reference)
//
#include <hip/hip_runtime.h>
#include <math.h>

#define TT 16
#define NN 50000
#define FF 128
#define BB 1024
#define S0C 10
#define S1C 5
#define H0C 128
#define H1C 64
#define CCC 10
#define R0C (BB + BB*S0C)   // 11264 layer-0 rows per timestep
#define BANDF 4e-3f         // fp32 worst-case GEMM error ~1e-4 -> 40x margin

// ---------------------------------------------------------------------------
// Kernel A: layer-0. Fused gather + neighbor mean + (self@Ws0 + neigh@Wn0 + b0)
// + spike threshold. fp32 fast path; outputs with |a0-1| < BANDF are pushed to
// a band list for exact fp64 recheck in kernel A2.
// Block: 256 threads, 64 rows x 128 cols. Grid: (176, 16). Rows r<B and r>=B
// never mix within a block (B = 1024 = 16*64).
// ---------------------------------------------------------------------------
__global__ __launch_bounds__(256, 2) void k_layer0(
    const float* __restrict__ x, const int* __restrict__ nodes,
    const int* __restrict__ nbr1, const int* __restrict__ nbr2,
    const float* __restrict__ Ws0, const float* __restrict__ Wn0,
    const float* __restrict__ b0,
    unsigned char* __restrict__ spk0,
    unsigned int* __restrict__ band_list, unsigned int* __restrict__ band_cnt,
    int band_cap)
{
  __shared__ float lself[64][128];
  __shared__ float lnh[64][128];
  const int t   = blockIdx.y;
  const int r0  = blockIdx.x * 64;
  const int tid = threadIdx.x;
  const float* xt = x + (size_t)t * NN * FF;

  { // ---- gather phase: 4 threads per row, 32 floats each ----
    const int rr = tid >> 2, tq = tid & 3, k0 = tq * 32;
    const int r  = r0 + rr;
    int sidx, S; const int* nb;
    if (r < BB) {
      sidx = nodes[r];
      nb = nbr1 + ((size_t)t * BB + r) * S0C;  S = S0C;
    } else {
      const int j = r - BB;
      sidx = nbr1[(size_t)t * BB * S0C + j];
      nb = nbr2 + ((size_t)t * BB * S0C + j) * S1C;  S = S1C;
    }
    const float4* srow = (const float4*)(xt + (size_t)sidx * FF + k0);
    #pragma unroll
    for (int q = 0; q < 8; q++) *(float4*)&lself[rr][k0 + q*4] = srow[q];

    float4 a[8];
    #pragma unroll
    for (int q = 0; q < 8; q++) a[q] = make_float4(0.f, 0.f, 0.f, 0.f);
    for (int s = 0; s < S; s++) {
      const float4* nr = (const float4*)(xt + (size_t)nb[s] * FF + k0);
      #pragma unroll
      for (int q = 0; q < 8; q++) {
        float4 v = nr[q];
        a[q].x += v.x; a[q].y += v.y; a[q].z += v.z; a[q].w += v.w;
      }
    }
    const float sc = 1.0f / (float)S;
    #pragma unroll
    for (int q = 0; q < 8; q++) {
      float4 v = a[q];
      v.x *= sc; v.y *= sc; v.z *= sc; v.w *= sc;
      *(float4*)&lnh[rr][k0 + q*4] = v;
    }
  }
  __syncthreads();

  // ---- GEMM phase: thread handles 8 rows x 4 cols ----
  const int cg  = (tid & 31) * 4;
  const int rr0 = (tid >> 5) * 8;
  float4 acc[8];
  #pragma unroll
  for (int i = 0; i < 8; i++) acc[i] = make_float4(0.f, 0.f, 0.f, 0.f);

  #pragma unroll 2
  for (int k = 0; k < FF; k++) {
    const float4 ws = *(const float4*)(Ws0 + k * H0C + cg);
    const float4 wn = *(const float4*)(Wn0 + k * H0C + cg);
    #pragma unroll
    for (int i = 0; i < 8; i++) {
      const float s = lself[rr0 + i][k];
      const float h = lnh[rr0 + i][k];
      acc[i].x = fmaf(s, ws.x, acc[i].x); acc[i].x = fmaf(h, wn.x, acc[i].x);
      acc[i].y = fmaf(s, ws.y, acc[i].y); acc[i].y = fmaf(h, wn.y, acc[i].y);
      acc[i].z = fmaf(s, ws.z, acc[i].z); acc[i].z = fmaf(h, wn.z, acc[i].z);
      acc[i].w = fmaf(s, ws.w, acc[i].w); acc[i].w = fmaf(h, wn.w, acc[i].w);
    }
  }

  const float4 bb = *(const float4*)(b0 + cg);
  #pragma unroll
  for (int i = 0; i < 8; i++) {
    const int r = r0 + rr0 + i;
    const unsigned gr = (unsigned)(t * R0C + r);
    float ax = acc[i].x + bb.x;
    float ay = acc[i].y + bb.y;
    float az = acc[i].z + bb.z;
    float aw = acc[i].w + bb.w;
    uchar4 sp;
    sp.x = (unsigned char)(ax >= 1.0f);
    sp.y = (unsigned char)(ay >= 1.0f);
    sp.z = (unsigned char)(az >= 1.0f);
    sp.w = (unsigned char)(aw >= 1.0f);
    *(uchar4*)(spk0 + (size_t)gr * H0C + cg) = sp;
    if (fabsf(ax - 1.0f) < BANDF) { unsigned idx = atomicAdd(band_cnt, 1u); if ((int)idx < band_cap) band_list[idx] = gr * 128u + (unsigned)(cg + 0); }
    if (fabsf(ay - 1.0f) < BANDF) { unsigned idx = atomicAdd(band_cnt, 1u); if ((int)idx < band_cap) band_list[idx] = gr * 128u + (unsigned)(cg + 1); }
    if (fabsf(az - 1.0f) < BANDF) { unsigned idx = atomicAdd(band_cnt, 1u); if ((int)idx < band_cap) band_list[idx] = gr * 128u + (unsigned)(cg + 2); }
    if (fabsf(aw - 1.0f) < BANDF) { unsigned idx = atomicAdd(band_cnt, 1u); if ((int)idx < band_cap) band_list[idx] = gr * 128u + (unsigned)(cg + 3); }
  }
}

// ---------------------------------------------------------------------------
// Kernel A2: exact fp64 recheck of band cases. One wave (64 lanes) per case;
// lane handles k = lane and lane+64; cross-lane fp64 reduce.
// ---------------------------------------------------------------------------
__global__ __launch_bounds__(64) void k_recheck(
    const float* __restrict__ x, const int* __restrict__ nodes,
    const int* __restrict__ nbr1, const int* __restrict__ nbr2,
    const float* __restrict__ Ws0, const float* __restrict__ Wn0,
    const float* __restrict__ b0,
    unsigned char* __restrict__ spk0,
    const unsigned int* __restrict__ band_list,
    const unsigned int* __restrict__ band_cnt, int band_cap)
{
  unsigned int n = *band_cnt;
  if (n > (unsigned)band_cap) n = (unsigned)band_cap;
  const int lane = threadIdx.x;
  for (unsigned int i = blockIdx.x; i < n; i += gridDim.x) {
    const unsigned int v = band_list[i];
    const int c = (int)(v & 127u);
    const unsigned int gr = v >> 7;
    const int t = (int)(gr / (unsigned)R0C);
    const int r = (int)(gr - (unsigned)t * (unsigned)R0C);
    const float* xt = x + (size_t)t * NN * FF;
    int sidx, S; const int* nb;
    if (r < BB) {
      sidx = nodes[r];
      nb = nbr1 + ((size_t)t * BB + r) * S0C;  S = S0C;
    } else {
      const int j = r - BB;
      sidx = nbr1[(size_t)t * BB * S0C + j];
      nb = nbr2 + ((size_t)t * BB * S0C + j) * S1C;  S = S1C;
    }
    double sum = 0.0;
    #pragma unroll
    for (int h = 0; h < 2; h++) {
      const int k = lane + h * 64;
      const double sv = (double)xt[(size_t)sidx * FF + k];
      double nv = 0.0;
      for (int s = 0; s < S; s++) nv += (double)xt[(size_t)nb[s] * FF + k];
      nv /= (double)S;
      sum += sv * (double)Ws0[k * H0C + c] + nv * (double)Wn0[k * H0C + c];
    }
    #pragma unroll
    for (int off = 32; off > 0; off >>= 1) sum += __shfl_down(sum, off);
    if (lane == 0) {
      const double a = sum + (double)b0[c];
      spk0[(size_t)gr * H0C + c] = (a >= 1.0) ? (unsigned char)1 : (unsigned char)0;
    }
  }
}

// ---------------------------------------------------------------------------
// Kernel B: layer-1, fully fp64 (inputs are exact 0/1 and exact counts, so
// fp64 accumulation matches the fp64 numpy reference to ~1e-16).
// Block: 256 threads (4 waves) handles (t, 16 b's); W1 matrices in LDS.
// ---------------------------------------------------------------------------
__global__ __launch_bounds__(256, 2) void k_layer1(
    const unsigned char* __restrict__ spk0,
    const float* __restrict__ Ws1, const float* __restrict__ Wn1,
    const float* __restrict__ b1, float* __restrict__ spk1)
{
  __shared__ float  WsL[H0C * H1C];
  __shared__ float  WnL[H0C * H1C];
  __shared__ float  ssf[4][H0C];
  __shared__ double md[4][H0C];
  const int tid   = threadIdx.x;
  const int t     = blockIdx.y;
  const int bbase = blockIdx.x * 16;
  for (int i = tid; i < H0C * H1C; i += 256) { WsL[i] = Ws1[i]; WnL[i] = Wn1[i]; }
  __syncthreads();
  const int wave = tid >> 6, lane = tid & 63;
  for (int it = 0; it < 4; it++) {
    const int b = bbase + it * 4 + wave;
    #pragma unroll
    for (int h = 0; h < 2; h++) {
      const int k = lane + h * 64;
      ssf[wave][k] = (float)spk0[((size_t)t * R0C + b) * H0C + k];
      int cnt = 0;
      for (int s = 0; s < S0C; s++)
        cnt += spk0[((size_t)t * R0C + BB + b * S0C + s) * H0C + k];
      md[wave][k] = (double)cnt / 10.0;   // matches np's fp64 sum/10
    }
    __syncthreads();
    double acc = (double)b1[lane];
    for (int k = 0; k < H0C; k++) {
      acc += (double)ssf[wave][k] * (double)WsL[k * H1C + lane];
      acc += md[wave][k] * (double)WnL[k * H1C + lane];
    }
    spk1[((size_t)b * TT + t) * H1C + lane] = (acc >= 1.0) ? 1.0f : 0.0f;
    __syncthreads();
  }
}

// ---------------------------------------------------------------------------
// Kernel C: delay mixing (softmax weights) + depthwise conv (SAME, K=5) +
// projection + bias. One block per b, thread d in [0,64). All fp64 (smooth
// path, no thresholds -> trivially within tolerance).
// ---------------------------------------------------------------------------
__global__ __launch_bounds__(64) void k_readout(
    const float* __restrict__ spk1, const float* __restrict__ logits,
    const float* __restrict__ dw, const float* __restrict__ pw,
    const float* __restrict__ tb, float* __restrict__ out)
{
  __shared__ double ysL[H1C];
  const int b = blockIdx.x, d = threadIdx.x;
  const float* lg = logits + (d >> 3) * 3;
  const double l0 = (double)lg[0], l1 = (double)lg[1], l2 = (double)lg[2];
  const double mx = fmax(l0, fmax(l1, l2));
  const double e0 = exp(l0 - mx), e1 = exp(l1 - mx), e2 = exp(l2 - mx);
  const double se = e0 + e1 + e2;
  const double w0 = e0 / se, w1 = e1 / se, w2 = e2 / se;

  float sp[TT];
  #pragma unroll
  for (int t = 0; t < TT; t++) sp[t] = spk1[((size_t)b * TT + t) * H1C + d];

  double dl[TT];
  #pragma unroll
  for (int t = 0; t < TT; t++) {
    double v = 0.0;
    if (t >= 1) v += (double)sp[t - 1] * w0;
    if (t >= 3) v += (double)sp[t - 3] * w1;
    if (t >= 5) v += (double)sp[t - 5] * w2;
    dl[t] = v;
  }
  double kw[5];
  #pragma unroll
  for (int k = 0; k < 5; k++) kw[k] = (double)dw[d * 5 + k];
  double ys = 0.0;
  #pragma unroll
  for (int t = 0; t < TT; t++) {
    double y = 0.0;
    #pragma unroll
    for (int k = 0; k < 5; k++) {
      const int t2 = t + k - 2;
      if (t2 >= 0 && t2 < TT) y += dl[t2] * kw[k];
    }
    ys += y;
  }
  ysL[d] = ys;
  __syncthreads();
  if (d < CCC) {
    double acc = 0.0;
    for (int dd = 0; dd < H1C; dd++) acc += ysL[dd] * (double)pw[dd * CCC + d];
    out[(size_t)b * CCC + d] = (float)(acc / (double)TT + (double)tb[d]);
  }
}

// ---------------------------------------------------------------------------
extern "C" void kernel_launch(void* const* d_in, const int* in_sizes, int n_in,
                              void* d_out, int out_size, void* d_ws, size_t ws_size,
                              hipStream_t stream)
{
  const float* x      = (const float*)d_in[0];
  const int*   nodes  = (const int*)d_in[1];
  const int*   nbr1   = (const int*)d_in[2];
  const int*   nbr2   = (const int*)d_in[3];
  const float* Ws0    = (const float*)d_in[4];
  const float* Wn0    = (const float*)d_in[5];
  const float* b0     = (const float*)d_in[6];
  const float* Ws1    = (const float*)d_in[7];
  const float* Wn1    = (const float*)d_in[8];
  const float* b1     = (const float*)d_in[9];
  const float* logits = (const float*)d_in[10];
  const float* dw     = (const float*)d_in[11];
  const float* pw     = (const float*)d_in[12];
  const float* tb     = (const float*)d_in[13];
  float* out = (float*)d_out;

  // workspace layout (all offsets 256B-aligned)
  char* ws = (char*)d_ws;
  unsigned char* spk0     = (unsigned char*)ws;                    // 23,068,672 B
  float*         spk1     = (float*)(ws + 23068672);               //  4,194,304 B
  unsigned int*  band_cnt = (unsigned int*)(ws + 27262976);        //          4 B
  unsigned int*  band_list= (unsigned int*)(ws + 27263232);
  const long long rem = (long long)ws_size - 27263232LL;
  const int band_cap = rem > 0 ? (int)((rem / 4 < (long long)(1 << 20)) ? rem / 4 : (long long)(1 << 20)) : 0;

  hipMemsetAsync(band_cnt, 0, 4, stream);
  k_layer0 <<<dim3(176, 16), 256, 0, stream>>>(x, nodes, nbr1, nbr2, Ws0, Wn0, b0,
                                               spk0, band_list, band_cnt, band_cap);
  k_recheck<<<dim3(2048),    64,  0, stream>>>(x, nodes, nbr1, nbr2, Ws0, Wn0, b0,
                                               spk0, band_list, band_cnt, band_cap);
  k_layer1 <<<dim3(64, 16),  256, 0, stream>>>(spk0, Ws1, Wn1, b1, spk1);
  k_readout<<<dim3(1024),    64,  0, stream>>>(spk1, logits, dw, pw, tb, out);
}

// Round 2
// 994.974 us; speedup vs baseline: 1.1417x; 1.1417x over previous
//
#include <hip/hip_runtime.h>
#include <math.h>

#define TT 16
#define NN 50000
#define FF 128
#define BB 1024
#define S0C 10
#define S1C 5
#define H0C 128
#define H1C 64
#define CCC 10
#define R0C (BB + BB*S0C)   // 11264 layer-0 rows per timestep
#define BANDF 4e-3f         // split-bf16 MFMA worst-case error ~5e-4 -> 8x margin

typedef __attribute__((ext_vector_type(8))) short bf16x8;
typedef __attribute__((ext_vector_type(4))) float f32x4;

__device__ __forceinline__ unsigned short bf16_rn(float f) {
  unsigned u = __float_as_uint(f);
  return (unsigned short)((u + 0x7FFFu + ((u >> 16) & 1u)) >> 16);
}
__device__ __forceinline__ void split2(float f, unsigned short& h, unsigned short& l) {
  h = bf16_rn(f);
  float hf = __uint_as_float((unsigned)h << 16);
  l = bf16_rn(f - hf);
}

// ---------------------------------------------------------------------------
// Prep: split Ws0/Wn0 (fp32, [k][n], K=256 concat) into bf16 hi/lo planes,
// pre-swizzled into MFMA B-fragment order:
//   idx = ((ks*8 + nt)*64 + (kq*16 + n16))*8 + j,  k = ks*32 + kq*8 + j, n = nt*16+n16
// hi plane at [0, 32768) ushort, lo plane at [32768, 65536).
// ---------------------------------------------------------------------------
__global__ __launch_bounds__(256) void k_prep_w(
    const float* __restrict__ Ws0, const float* __restrict__ Wn0,
    unsigned short* __restrict__ Wswz)
{
  const int id = blockIdx.x * 256 + threadIdx.x;   // 32768 total
  if (id >= 256 * 128) return;
  const int k = id >> 7, n = id & 127;
  const float wv = (k < 128) ? Ws0[k * H0C + n] : Wn0[(k - 128) * H0C + n];
  unsigned short h, l;
  split2(wv, h, l);
  const int ks = k >> 5, kq = (k >> 3) & 3, j = k & 7;
  const int nt = n >> 4, n16 = n & 15;
  const int idx = (((ks * 8 + nt) * 64) + (kq * 16 + n16)) * 8 + j;
  Wswz[idx] = h;
  Wswz[32768 + idx] = l;
}

// ---------------------------------------------------------------------------
// Kernel A: layer-0 fused gather + neighbor-mean + split-bf16 MFMA GEMM +
// threshold + band push. Block 256 thr (4 waves), tile 64 rows x 128 cols,
// K=256 (self|neigh). LDS: bf16 hi/lo A-tiles, XOR-chunk swizzled, 64 KB.
// ---------------------------------------------------------------------------
__global__ __launch_bounds__(256, 2) void k_layer0(
    const float* __restrict__ x, const int* __restrict__ nodes,
    const int* __restrict__ nbr1, const int* __restrict__ nbr2,
    const unsigned short* __restrict__ Wswz, const float* __restrict__ b0,
    unsigned char* __restrict__ spk0,
    unsigned int* __restrict__ band_list, unsigned int* __restrict__ band_cnt,
    int band_cap)
{
  __shared__ __align__(16) unsigned short Abf[2 * 64 * 256];  // hi | lo planes
  const int t   = blockIdx.y;
  const int r0  = blockIdx.x * 64;
  const int tid = threadIdx.x;
  const float* xt = x + (size_t)t * NN * FF;

  { // ---- gather phase: 4 threads per row, 32 floats (4 chunks of 8) each ----
    const int rr = tid >> 2, tq = tid & 3, k0 = tq * 32;
    const int r  = r0 + rr;
    const int sw = rr & 7;
    const float* srow;
    float inv;
    int S;
    int ids[10];
    if (r < BB) {
      srow = xt + (size_t)nodes[r] * FF + k0;
      const int* nb = nbr1 + ((size_t)t * BB + r) * S0C;
      #pragma unroll
      for (int s = 0; s < 10; s++) ids[s] = nb[s];
      S = 10; inv = 0.1f;
    } else {
      const int j = r - BB;
      srow = xt + (size_t)nbr1[(size_t)t * BB * S0C + j] * FF + k0;
      const int* nb = nbr2 + ((size_t)t * BB * S0C + j) * S1C;
      #pragma unroll
      for (int s = 0; s < 5; s++) ids[s] = nb[s];
      S = 5; inv = 0.2f;
    }
    // neighbor accumulation, two rows per iteration for MLP
    float4 a[8];
    #pragma unroll
    for (int q = 0; q < 8; q++) a[q] = make_float4(0.f, 0.f, 0.f, 0.f);
    int s = 0;
    for (; s + 2 <= S; s += 2) {
      const float4* rA = (const float4*)(xt + (size_t)ids[s]     * FF + k0);
      const float4* rB = (const float4*)(xt + (size_t)ids[s + 1] * FF + k0);
      float4 va[8], vb[8];
      #pragma unroll
      for (int q = 0; q < 8; q++) va[q] = rA[q];
      #pragma unroll
      for (int q = 0; q < 8; q++) vb[q] = rB[q];
      #pragma unroll
      for (int q = 0; q < 8; q++) {
        a[q].x += va[q].x + vb[q].x; a[q].y += va[q].y + vb[q].y;
        a[q].z += va[q].z + vb[q].z; a[q].w += va[q].w + vb[q].w;
      }
    }
    if (s < S) {
      const float4* rA = (const float4*)(xt + (size_t)ids[s] * FF + k0);
      #pragma unroll
      for (int q = 0; q < 8; q++) {
        float4 v = rA[q];
        a[q].x += v.x; a[q].y += v.y; a[q].z += v.z; a[q].w += v.w;
      }
    }
    // write neighbor chunks (c = 16 + tq*4 + ch)
    #pragma unroll
    for (int ch = 0; ch < 4; ch++) {
      float v[8] = { a[2*ch].x * inv, a[2*ch].y * inv, a[2*ch].z * inv, a[2*ch].w * inv,
                     a[2*ch+1].x * inv, a[2*ch+1].y * inv, a[2*ch+1].z * inv, a[2*ch+1].w * inv };
      unsigned short h[8], l[8];
      #pragma unroll
      for (int e = 0; e < 8; e++) split2(v[e], h[e], l[e]);
      const int c = 16 + tq * 4 + ch;
      const int idx = rr * 256 + ((c ^ sw) << 3);
      uint4 HW = { (unsigned)h[0] | ((unsigned)h[1] << 16), (unsigned)h[2] | ((unsigned)h[3] << 16),
                   (unsigned)h[4] | ((unsigned)h[5] << 16), (unsigned)h[6] | ((unsigned)h[7] << 16) };
      uint4 LW = { (unsigned)l[0] | ((unsigned)l[1] << 16), (unsigned)l[2] | ((unsigned)l[3] << 16),
                   (unsigned)l[4] | ((unsigned)l[5] << 16), (unsigned)l[6] | ((unsigned)l[7] << 16) };
      *(uint4*)&Abf[idx] = HW;
      *(uint4*)&Abf[16384 + idx] = LW;
    }
    // self chunks (c = tq*4 + ch)
    float4 sv[8];
    const float4* sp4 = (const float4*)srow;
    #pragma unroll
    for (int q = 0; q < 8; q++) sv[q] = sp4[q];
    #pragma unroll
    for (int ch = 0; ch < 4; ch++) {
      float v[8] = { sv[2*ch].x, sv[2*ch].y, sv[2*ch].z, sv[2*ch].w,
                     sv[2*ch+1].x, sv[2*ch+1].y, sv[2*ch+1].z, sv[2*ch+1].w };
      unsigned short h[8], l[8];
      #pragma unroll
      for (int e = 0; e < 8; e++) split2(v[e], h[e], l[e]);
      const int c = tq * 4 + ch;
      const int idx = rr * 256 + ((c ^ sw) << 3);
      uint4 HW = { (unsigned)h[0] | ((unsigned)h[1] << 16), (unsigned)h[2] | ((unsigned)h[3] << 16),
                   (unsigned)h[4] | ((unsigned)h[5] << 16), (unsigned)h[6] | ((unsigned)h[7] << 16) };
      uint4 LW = { (unsigned)l[0] | ((unsigned)l[1] << 16), (unsigned)l[2] | ((unsigned)l[3] << 16),
                   (unsigned)l[4] | ((unsigned)l[5] << 16), (unsigned)l[6] | ((unsigned)l[7] << 16) };
      *(uint4*)&Abf[idx] = HW;
      *(uint4*)&Abf[16384 + idx] = LW;
    }
  }
  __syncthreads();

  // ---- MFMA phase: wave w owns rows w*16..+15, all 128 cols ----
  const int w = tid >> 6, l = tid & 63, m16 = l & 15, quad = l >> 4;
  const int rowl = w * 16 + m16;
  const unsigned short* ArowH = Abf + rowl * 256;
  const unsigned short* ArowL = Abf + 16384 + rowl * 256;
  const int sw = m16 & 7;   // (w*16+m16)&7 == m16&7
  f32x4 acc[8];
  #pragma unroll
  for (int nt = 0; nt < 8; nt++) acc[nt] = (f32x4){0.f, 0.f, 0.f, 0.f};

  for (int ks = 0; ks < 8; ks++) {
    const int c = ks * 4 + quad;
    const int off = (c ^ sw) << 3;
    bf16x8 ah = *(const bf16x8*)(ArowH + off);
    bf16x8 al = *(const bf16x8*)(ArowL + off);
    const unsigned short* wp = Wswz + ((size_t)(ks * 8) * 64 + l) * 8;
    #pragma unroll
    for (int nt = 0; nt < 8; nt++) {
      bf16x8 bh = *(const bf16x8*)(wp + nt * 512);
      bf16x8 bl = *(const bf16x8*)(wp + 32768 + nt * 512);
      acc[nt] = __builtin_amdgcn_mfma_f32_16x16x32_bf16(ah, bh, acc[nt], 0, 0, 0);
      acc[nt] = __builtin_amdgcn_mfma_f32_16x16x32_bf16(al, bh, acc[nt], 0, 0, 0);
      acc[nt] = __builtin_amdgcn_mfma_f32_16x16x32_bf16(ah, bl, acc[nt], 0, 0, 0);
    }
  }

  // ---- epilogue: D[row=(quad*4+i)][col=m16] per 16x16 tile ----
  #pragma unroll
  for (int nt = 0; nt < 8; nt++) {
    const int c = nt * 16 + m16;
    const float bc = b0[c];
    #pragma unroll
    for (int i = 0; i < 4; i++) {
      const int r = r0 + w * 16 + quad * 4 + i;
      const unsigned gr = (unsigned)(t * R0C + r);
      const float av = acc[nt][i] + bc;
      spk0[(size_t)gr * H0C + c] = (unsigned char)(av >= 1.0f);
      if (fabsf(av - 1.0f) < BANDF) {
        unsigned idx = atomicAdd(band_cnt, 1u);
        if ((int)idx < band_cap) band_list[idx] = gr * 128u + (unsigned)c;
      }
    }
  }
}

// ---------------------------------------------------------------------------
// Kernel A2: exact fp64 recheck of band cases. One wave per case; templated
// neighbor count so all loads unroll and stay in flight.
// ---------------------------------------------------------------------------
template<int S>
__device__ __forceinline__ double band_dot(
    const float* xt, int sidx, const int* nb,
    const float* Ws0, const float* Wn0, int c, int lane)
{
  int ids[S];
  #pragma unroll
  for (int s = 0; s < S; s++) ids[s] = nb[s];
  double sum = 0.0;
  #pragma unroll
  for (int h = 0; h < 2; h++) {
    const int k = lane + h * 64;
    const double svv = (double)xt[(size_t)sidx * FF + k];
    double nv = 0.0;
    #pragma unroll
    for (int s = 0; s < S; s++) nv += (double)xt[(size_t)ids[s] * FF + k];
    sum += svv * (double)Ws0[k * H0C + c] + (nv / (double)S) * (double)Wn0[k * H0C + c];
  }
  return sum;
}

__global__ __launch_bounds__(64) void k_recheck(
    const float* __restrict__ x, const int* __restrict__ nodes,
    const int* __restrict__ nbr1, const int* __restrict__ nbr2,
    const float* __restrict__ Ws0, const float* __restrict__ Wn0,
    const float* __restrict__ b0,
    unsigned char* __restrict__ spk0,
    const unsigned int* __restrict__ band_list,
    const unsigned int* __restrict__ band_cnt, int band_cap)
{
  unsigned int n = *band_cnt;
  if (n > (unsigned)band_cap) n = (unsigned)band_cap;
  const int lane = threadIdx.x;
  for (unsigned int i = blockIdx.x; i < n; i += gridDim.x) {
    const unsigned int v = band_list[i];
    const int c = (int)(v & 127u);
    const unsigned int gr = v >> 7;
    const int t = (int)(gr / (unsigned)R0C);
    const int r = (int)(gr - (unsigned)t * (unsigned)R0C);
    const float* xt = x + (size_t)t * NN * FF;
    double sum;
    if (r < BB) {
      sum = band_dot<S0C>(xt, nodes[r], nbr1 + ((size_t)t * BB + r) * S0C,
                          Ws0, Wn0, c, lane);
    } else {
      const int j = r - BB;
      sum = band_dot<S1C>(xt, nbr1[(size_t)t * BB * S0C + j],
                          nbr2 + ((size_t)t * BB * S0C + j) * S1C,
                          Ws0, Wn0, c, lane);
    }
    #pragma unroll
    for (int off = 32; off > 0; off >>= 1) sum += __shfl_down(sum, off);
    if (lane == 0) {
      const double a = sum + (double)b0[c];
      spk0[(size_t)gr * H0C + c] = (a >= 1.0) ? (unsigned char)1 : (unsigned char)0;
    }
  }
}

// ---------------------------------------------------------------------------
// Kernel B: layer-1, fp64 exact (inputs are exact 0/1 and exact counts).
// 4-way split accumulator chain for ILP.
// ---------------------------------------------------------------------------
__global__ __launch_bounds__(256, 2) void k_layer1(
    const unsigned char* __restrict__ spk0,
    const float* __restrict__ Ws1, const float* __restrict__ Wn1,
    const float* __restrict__ b1, float* __restrict__ spk1)
{
  __shared__ float  WsL[H0C * H1C];
  __shared__ float  WnL[H0C * H1C];
  __shared__ float  ssf[4][H0C];
  __shared__ double md[4][H0C];
  const int tid   = threadIdx.x;
  const int t     = blockIdx.y;
  const int bbase = blockIdx.x * 16;
  for (int i = tid; i < H0C * H1C; i += 256) { WsL[i] = Ws1[i]; WnL[i] = Wn1[i]; }
  __syncthreads();
  const int wave = tid >> 6, lane = tid & 63;
  for (int it = 0; it < 4; it++) {
    const int b = bbase + it * 4 + wave;
    #pragma unroll
    for (int h = 0; h < 2; h++) {
      const int k = lane + h * 64;
      ssf[wave][k] = (float)spk0[((size_t)t * R0C + b) * H0C + k];
      int cnt = 0;
      #pragma unroll
      for (int s = 0; s < S0C; s++)
        cnt += spk0[((size_t)t * R0C + BB + b * S0C + s) * H0C + k];
      md[wave][k] = (double)cnt / 10.0;
    }
    __syncthreads();
    double aS0 = 0.0, aS1 = 0.0, aN0 = 0.0, aN1 = 0.0;
    #pragma unroll 4
    for (int k = 0; k < H0C; k += 2) {
      aS0 += (double)ssf[wave][k]     * (double)WsL[k * H1C + lane];
      aS1 += (double)ssf[wave][k + 1] * (double)WsL[(k + 1) * H1C + lane];
      aN0 += md[wave][k]     * (double)WnL[k * H1C + lane];
      aN1 += md[wave][k + 1] * (double)WnL[(k + 1) * H1C + lane];
    }
    const double acc = (double)b1[lane] + ((aS0 + aS1) + (aN0 + aN1));
    spk1[((size_t)b * TT + t) * H1C + lane] = (acc >= 1.0) ? 1.0f : 0.0f;
    __syncthreads();
  }
}

// ---------------------------------------------------------------------------
// Kernel C: delay mixing + depthwise conv + projection, fp64 (smooth path).
// ---------------------------------------------------------------------------
__global__ __launch_bounds__(64) void k_readout(
    const float* __restrict__ spk1, const float* __restrict__ logits,
    const float* __restrict__ dw, const float* __restrict__ pw,
    const float* __restrict__ tb, float* __restrict__ out)
{
  __shared__ double ysL[H1C];
  const int b = blockIdx.x, d = threadIdx.x;
  const float* lg = logits + (d >> 3) * 3;
  const double l0 = (double)lg[0], l1 = (double)lg[1], l2 = (double)lg[2];
  const double mx = fmax(l0, fmax(l1, l2));
  const double e0 = exp(l0 - mx), e1 = exp(l1 - mx), e2 = exp(l2 - mx);
  const double se = e0 + e1 + e2;
  const double w0 = e0 / se, w1 = e1 / se, w2 = e2 / se;

  float sp[TT];
  #pragma unroll
  for (int t = 0; t < TT; t++) sp[t] = spk1[((size_t)b * TT + t) * H1C + d];

  double dl[TT];
  #pragma unroll
  for (int t = 0; t < TT; t++) {
    double v = 0.0;
    if (t >= 1) v += (double)sp[t - 1] * w0;
    if (t >= 3) v += (double)sp[t - 3] * w1;
    if (t >= 5) v += (double)sp[t - 5] * w2;
    dl[t] = v;
  }
  double kw[5];
  #pragma unroll
  for (int k = 0; k < 5; k++) kw[k] = (double)dw[d * 5 + k];
  double ys = 0.0;
  #pragma unroll
  for (int t = 0; t < TT; t++) {
    double y = 0.0;
    #pragma unroll
    for (int k = 0; k < 5; k++) {
      const int t2 = t + k - 2;
      if (t2 >= 0 && t2 < TT) y += dl[t2] * kw[k];
    }
    ys += y;
  }
  ysL[d] = ys;
  __syncthreads();
  if (d < CCC) {
    double acc = 0.0;
    for (int dd = 0; dd < H1C; dd++) acc += ysL[dd] * (double)pw[dd * CCC + d];
    out[(size_t)b * CCC + d] = (float)(acc / (double)TT + (double)tb[d]);
  }
}

// ---------------------------------------------------------------------------
extern "C" void kernel_launch(void* const* d_in, const int* in_sizes, int n_in,
                              void* d_out, int out_size, void* d_ws, size_t ws_size,
                              hipStream_t stream)
{
  const float* x      = (const float*)d_in[0];
  const int*   nodes  = (const int*)d_in[1];
  const int*   nbr1   = (const int*)d_in[2];
  const int*   nbr2   = (const int*)d_in[3];
  const float* Ws0    = (const float*)d_in[4];
  const float* Wn0    = (const float*)d_in[5];
  const float* b0     = (const float*)d_in[6];
  const float* Ws1    = (const float*)d_in[7];
  const float* Wn1    = (const float*)d_in[8];
  const float* b1     = (const float*)d_in[9];
  const float* logits = (const float*)d_in[10];
  const float* dw     = (const float*)d_in[11];
  const float* pw     = (const float*)d_in[12];
  const float* tb     = (const float*)d_in[13];
  float* out = (float*)d_out;

  // workspace layout (256B-aligned offsets)
  char* ws = (char*)d_ws;
  unsigned char*  spk0      = (unsigned char*)ws;                 // 23,068,672 B
  float*          spk1      = (float*)(ws + 23068672);            //  4,194,304 B
  unsigned short* Wswz      = (unsigned short*)(ws + 27262976);   //    131,072 B
  unsigned int*   band_cnt  = (unsigned int*)(ws + 27394048);     //          4 B
  unsigned int*   band_list = (unsigned int*)(ws + 27394304);
  const long long rem = (long long)ws_size - 27394304LL;
  const int band_cap = rem > 0 ? (int)((rem / 4 < (long long)(1 << 20)) ? rem / 4 : (long long)(1 << 20)) : 0;

  hipMemsetAsync(band_cnt, 0, 4, stream);
  k_prep_w <<<dim3(128),      256, 0, stream>>>(Ws0, Wn0, Wswz);
  k_layer0 <<<dim3(176, 16),  256, 0, stream>>>(x, nodes, nbr1, nbr2, Wswz, b0,
                                                spk0, band_list, band_cnt, band_cap);
  k_recheck<<<dim3(2048),     64,  0, stream>>>(x, nodes, nbr1, nbr2, Ws0, Wn0, b0,
                                                spk0, band_list, band_cnt, band_cap);
  k_layer1 <<<dim3(64, 16),   256, 0, stream>>>(spk0, Ws1, Wn1, b1, spk1);
  k_readout<<<dim3(1024),     64,  0, stream>>>(spk1, logits, dw, pw, tb, out);
}

// Round 3
// 820.057 us; speedup vs baseline: 1.3852x; 1.2133x over previous
//
#include <hip/hip_runtime.h>
#include <math.h>

#define TT 16
#define NN 50000
#define FF 128
#define BB 1024
#define S0C 10
#define S1C 5
#define H0C 128
#define H1C 64
#define CCC 10
#define R0C (BB + BB*S0C)   // 11264 layer-0 rows per timestep
#define BANDF 2e-3f         // split-bf16 MFMA worst-case error ~2.5e-4 -> 8x margin

typedef __attribute__((ext_vector_type(8))) short bf16x8;
typedef __attribute__((ext_vector_type(4))) float f32x4;

__device__ __forceinline__ unsigned short bf16_rn(float f) {
  unsigned u = __float_as_uint(f);
  return (unsigned short)((u + 0x7FFFu + ((u >> 16) & 1u)) >> 16);
}
__device__ __forceinline__ void split2(float f, unsigned short& h, unsigned short& l) {
  h = bf16_rn(f);
  float hf = __uint_as_float((unsigned)h << 16);
  l = bf16_rn(f - hf);
}

// ---------------------------------------------------------------------------
// Prep: split Ws0/Wn0 into bf16 hi/lo planes in MFMA B-fragment order
// (idx = ((ks*8+nt)*64 + (kq*16+n16))*8 + j, k = ks*32+kq*8+j, n = nt*16+n16;
//  hi plane [0,32768) ushort, lo plane [32768,65536)). Also emits transposed
// fp32 copies WsT/WnT (c-major) for the coalesced fp64 recheck, and zeroes
// band_cnt (absorbs the former memset dispatch).
// ---------------------------------------------------------------------------
__global__ __launch_bounds__(256) void k_prep_w(
    const float* __restrict__ Ws0, const float* __restrict__ Wn0,
    unsigned short* __restrict__ Wswz,
    float* __restrict__ WsT, float* __restrict__ WnT,
    unsigned int* __restrict__ band_cnt)
{
  const int id = blockIdx.x * 256 + threadIdx.x;   // 32768 total
  if (id == 0) *band_cnt = 0u;
  if (id >= 256 * 128) return;
  const int k = id >> 7, n = id & 127;
  const float wv = (k < 128) ? Ws0[k * H0C + n] : Wn0[(k - 128) * H0C + n];
  if (k < 128) WsT[n * 128 + k] = wv;
  else         WnT[n * 128 + (k - 128)] = wv;
  unsigned short h, l;
  split2(wv, h, l);
  const int ks = k >> 5, kq = (k >> 3) & 3, j = k & 7;
  const int nt = n >> 4, n16 = n & 15;
  const int idx = (((ks * 8 + nt) * 64) + (kq * 16 + n16)) * 8 + j;
  Wswz[idx] = h;
  Wswz[32768 + idx] = l;
}

// ---------------------------------------------------------------------------
// Layer-0 helpers
// ---------------------------------------------------------------------------
__device__ __forceinline__ void split_write4(
    unsigned short* __restrict__ Abf, int rr, int tq,
    const float4 a[8], float inv)
{
  const int sw = rr & 7;
  #pragma unroll
  for (int ch = 0; ch < 4; ch++) {
    float v[8] = { a[2*ch].x * inv, a[2*ch].y * inv, a[2*ch].z * inv, a[2*ch].w * inv,
                   a[2*ch+1].x * inv, a[2*ch+1].y * inv, a[2*ch+1].z * inv, a[2*ch+1].w * inv };
    unsigned short h[8], l[8];
    #pragma unroll
    for (int e = 0; e < 8; e++) split2(v[e], h[e], l[e]);
    const int c = tq * 4 + ch;
    const int idx = rr * 128 + ((c ^ sw) << 3);
    uint4 HW = { (unsigned)h[0] | ((unsigned)h[1] << 16), (unsigned)h[2] | ((unsigned)h[3] << 16),
                 (unsigned)h[4] | ((unsigned)h[5] << 16), (unsigned)h[6] | ((unsigned)h[7] << 16) };
    uint4 LW = { (unsigned)l[0] | ((unsigned)l[1] << 16), (unsigned)l[2] | ((unsigned)l[3] << 16),
                 (unsigned)l[4] | ((unsigned)l[5] << 16), (unsigned)l[6] | ((unsigned)l[7] << 16) };
    *(uint4*)&Abf[idx] = HW;
    *(uint4*)&Abf[8192 + idx] = LW;
  }
}

template<int S>
__device__ __forceinline__ void gather_neigh_half(
    const float* __restrict__ xt, const int* __restrict__ nb, float inv,
    unsigned short* __restrict__ Abf, int rr, int tq)
{
  const int k0 = tq * 32;
  int ids[S];
  #pragma unroll
  for (int s = 0; s < S; s++) ids[s] = nb[s];
  float4 a[8];
  #pragma unroll
  for (int q = 0; q < 8; q++) a[q] = make_float4(0.f, 0.f, 0.f, 0.f);
  #pragma unroll
  for (int s = 0; s < S; s++) {
    const float4* rA = (const float4*)(xt + (size_t)ids[s] * FF + k0);
    float4 v[8];
    #pragma unroll
    for (int q = 0; q < 8; q++) v[q] = rA[q];
    #pragma unroll
    for (int q = 0; q < 8; q++) {
      a[q].x += v[q].x; a[q].y += v[q].y; a[q].z += v[q].z; a[q].w += v[q].w;
    }
  }
  split_write4(Abf, rr, tq, a, inv);
}

__device__ __forceinline__ void mfma_half(
    const unsigned short* __restrict__ ArowH,
    const unsigned short* __restrict__ ArowL,
    const unsigned short* __restrict__ Wswz,
    int half, int l, int quad, int swm, f32x4 acc[8])
{
  #pragma unroll
  for (int ksl = 0; ksl < 4; ksl++) {
    const int c = ksl * 4 + quad;
    const int off = (c ^ swm) << 3;
    bf16x8 ah = *(const bf16x8*)(ArowH + off);
    bf16x8 al = *(const bf16x8*)(ArowL + off);
    const unsigned short* wp = Wswz + ((size_t)((half * 4 + ksl) * 8) * 64 + l) * 8;
    #pragma unroll
    for (int nt = 0; nt < 8; nt++) {
      bf16x8 bh = *(const bf16x8*)(wp + nt * 512);
      bf16x8 bl = *(const bf16x8*)(wp + 32768 + nt * 512);
      acc[nt] = __builtin_amdgcn_mfma_f32_16x16x32_bf16(ah, bh, acc[nt], 0, 0, 0);
      acc[nt] = __builtin_amdgcn_mfma_f32_16x16x32_bf16(al, bh, acc[nt], 0, 0, 0);
      acc[nt] = __builtin_amdgcn_mfma_f32_16x16x32_bf16(ah, bl, acc[nt], 0, 0, 0);
    }
  }
}

// ---------------------------------------------------------------------------
// Kernel A: layer-0. K=256 processed as two 128-halves (self | neigh) through
// one 32 KB LDS A-buffer -> 3 blocks/CU (12 waves) for latency hiding.
// Neighbor gather fully unrolled (block-uniform S).
// ---------------------------------------------------------------------------
__global__ __launch_bounds__(256, 3) void k_layer0(
    const float* __restrict__ x, const int* __restrict__ nodes,
    const int* __restrict__ nbr1, const int* __restrict__ nbr2,
    const unsigned short* __restrict__ Wswz, const float* __restrict__ b0,
    unsigned char* __restrict__ spk0,
    unsigned int* __restrict__ band_list, unsigned int* __restrict__ band_cnt,
    int band_cap)
{
  __shared__ __align__(16) unsigned short Abf[2 * 64 * 128];  // 32 KB: hi | lo
  const int t   = blockIdx.y;
  const int r0  = blockIdx.x * 64;
  const int tid = threadIdx.x;
  const float* xt = x + (size_t)t * NN * FF;
  const int rr = tid >> 2, tq = tid & 3, k0 = tq * 32;
  const int r  = r0 + rr;

  const int w = tid >> 6, l = tid & 63, m16 = l & 15, quad = l >> 4;
  const int rowl = w * 16 + m16;
  const unsigned short* ArowH = Abf + rowl * 128;
  const unsigned short* ArowL = Abf + 8192 + rowl * 128;
  const int swm = m16 & 7;
  f32x4 acc[8];
  #pragma unroll
  for (int nt = 0; nt < 8; nt++) acc[nt] = (f32x4){0.f, 0.f, 0.f, 0.f};

  // ---- half 0: self rows ----
  {
    const float* srow;
    if (r < BB) srow = xt + (size_t)nodes[r] * FF + k0;
    else        srow = xt + (size_t)nbr1[(size_t)t * BB * S0C + (r - BB)] * FF + k0;
    const float4* sp4 = (const float4*)srow;
    float4 sv[8];
    #pragma unroll
    for (int q = 0; q < 8; q++) sv[q] = sp4[q];
    split_write4(Abf, rr, tq, sv, 1.0f);
  }
  __syncthreads();
  mfma_half(ArowH, ArowL, Wswz, 0, l, quad, swm, acc);
  __syncthreads();   // LDS reads done before overwrite

  // ---- half 1: neighbor means ----
  if (r < BB)
    gather_neigh_half<S0C>(xt, nbr1 + ((size_t)t * BB + r) * S0C, 0.1f, Abf, rr, tq);
  else
    gather_neigh_half<S1C>(xt, nbr2 + ((size_t)t * BB * S0C + (r - BB)) * S1C, 0.2f, Abf, rr, tq);
  __syncthreads();
  mfma_half(ArowH, ArowL, Wswz, 1, l, quad, swm, acc);

  // ---- epilogue: D[row=quad*4+i][col=m16] per 16x16 tile ----
  #pragma unroll
  for (int nt = 0; nt < 8; nt++) {
    const int c = nt * 16 + m16;
    const float bc = b0[c];
    #pragma unroll
    for (int i = 0; i < 4; i++) {
      const int rr2 = r0 + w * 16 + quad * 4 + i;
      const unsigned gr = (unsigned)(t * R0C + rr2);
      const float av = acc[nt][i] + bc;
      spk0[(size_t)gr * H0C + c] = (unsigned char)(av >= 1.0f);
      if (fabsf(av - 1.0f) < BANDF) {
        unsigned idx = atomicAdd(band_cnt, 1u);
        if ((int)idx < band_cap) band_list[idx] = gr * 128u + (unsigned)c;
      }
    }
  }
}

// ---------------------------------------------------------------------------
// Kernel A2: exact fp64 recheck of band cases (coalesced transposed weights).
// ---------------------------------------------------------------------------
template<int S>
__device__ __forceinline__ double band_dot(
    const float* xt, int sidx, const int* nb,
    const float* WsT, const float* WnT, int c, int lane)
{
  int ids[S];
  #pragma unroll
  for (int s = 0; s < S; s++) ids[s] = nb[s];
  double sum = 0.0;
  #pragma unroll
  for (int h = 0; h < 2; h++) {
    const int k = lane + h * 64;
    const double svv = (double)xt[(size_t)sidx * FF + k];
    double nv = 0.0;
    #pragma unroll
    for (int s = 0; s < S; s++) nv += (double)xt[(size_t)ids[s] * FF + k];
    sum += svv * (double)WsT[c * 128 + k] + (nv / (double)S) * (double)WnT[c * 128 + k];
  }
  return sum;
}

__global__ __launch_bounds__(64) void k_recheck(
    const float* __restrict__ x, const int* __restrict__ nodes,
    const int* __restrict__ nbr1, const int* __restrict__ nbr2,
    const float* __restrict__ WsT, const float* __restrict__ WnT,
    const float* __restrict__ b0,
    unsigned char* __restrict__ spk0,
    const unsigned int* __restrict__ band_list,
    const unsigned int* __restrict__ band_cnt, int band_cap)
{
  unsigned int n = *band_cnt;
  if (n > (unsigned)band_cap) n = (unsigned)band_cap;
  const int lane = threadIdx.x;
  for (unsigned int i = blockIdx.x; i < n; i += gridDim.x) {
    const unsigned int v = band_list[i];
    const int c = (int)(v & 127u);
    const unsigned int gr = v >> 7;
    const int t = (int)(gr / (unsigned)R0C);
    const int r = (int)(gr - (unsigned)t * (unsigned)R0C);
    const float* xt = x + (size_t)t * NN * FF;
    double sum;
    if (r < BB) {
      sum = band_dot<S0C>(xt, nodes[r], nbr1 + ((size_t)t * BB + r) * S0C,
                          WsT, WnT, c, lane);
    } else {
      const int j = r - BB;
      sum = band_dot<S1C>(xt, nbr1[(size_t)t * BB * S0C + j],
                          nbr2 + ((size_t)t * BB * S0C + j) * S1C,
                          WsT, WnT, c, lane);
    }
    #pragma unroll
    for (int off = 32; off > 0; off >>= 1) sum += __shfl_down(sum, off);
    if (lane == 0) {
      const double a = sum + (double)b0[c];
      spk0[(size_t)gr * H0C + c] = (a >= 1.0) ? (unsigned char)1 : (unsigned char)0;
    }
  }
}

// ---------------------------------------------------------------------------
// Kernel B: layer-1, fp64 exact. Grid (16,16): block = (64 b's, one t);
// weights staged once per block (float4); per-wave LDS slots, no inner
// barriers (waves never share slots).
// ---------------------------------------------------------------------------
__global__ __launch_bounds__(256, 2) void k_layer1(
    const unsigned char* __restrict__ spk0,
    const float* __restrict__ Ws1, const float* __restrict__ Wn1,
    const float* __restrict__ b1, float* __restrict__ spk1)
{
  __shared__ float  WsL[H0C * H1C];
  __shared__ float  WnL[H0C * H1C];
  __shared__ float  ssf[4][H0C];
  __shared__ double md[4][H0C];
  const int tid   = threadIdx.x;
  const int t     = blockIdx.y;
  const int bbase = blockIdx.x * 64;
  {
    const float4* s4 = (const float4*)Ws1;
    const float4* n4 = (const float4*)Wn1;
    float4* sL = (float4*)WsL;
    float4* nL = (float4*)WnL;
    for (int i = tid; i < H0C * H1C / 4; i += 256) { sL[i] = s4[i]; nL[i] = n4[i]; }
  }
  __syncthreads();
  const int wave = tid >> 6, lane = tid & 63;
  for (int it = 0; it < 16; it++) {
    const int b = bbase + it * 4 + wave;
    #pragma unroll
    for (int h = 0; h < 2; h++) {
      const int k = lane + h * 64;
      ssf[wave][k] = (float)spk0[((size_t)t * R0C + b) * H0C + k];
      int cnt = 0;
      #pragma unroll
      for (int s = 0; s < S0C; s++)
        cnt += spk0[((size_t)t * R0C + BB + b * S0C + s) * H0C + k];
      md[wave][k] = (double)cnt / 10.0;
    }
    double aS0 = 0.0, aS1 = 0.0, aN0 = 0.0, aN1 = 0.0;
    #pragma unroll 4
    for (int k = 0; k < H0C; k += 2) {
      aS0 += (double)ssf[wave][k]     * (double)WsL[k * H1C + lane];
      aS1 += (double)ssf[wave][k + 1] * (double)WsL[(k + 1) * H1C + lane];
      aN0 += md[wave][k]     * (double)WnL[k * H1C + lane];
      aN1 += md[wave][k + 1] * (double)WnL[(k + 1) * H1C + lane];
    }
    const double acc = (double)b1[lane] + ((aS0 + aS1) + (aN0 + aN1));
    spk1[((size_t)b * TT + t) * H1C + lane] = (acc >= 1.0) ? 1.0f : 0.0f;
  }
}

// ---------------------------------------------------------------------------
// Kernel C: delay mixing + depthwise conv + projection, fp64 (smooth path).
// ---------------------------------------------------------------------------
__global__ __launch_bounds__(64) void k_readout(
    const float* __restrict__ spk1, const float* __restrict__ logits,
    const float* __restrict__ dw, const float* __restrict__ pw,
    const float* __restrict__ tb, float* __restrict__ out)
{
  __shared__ double ysL[H1C];
  const int b = blockIdx.x, d = threadIdx.x;
  const float* lg = logits + (d >> 3) * 3;
  const double l0 = (double)lg[0], l1 = (double)lg[1], l2 = (double)lg[2];
  const double mx = fmax(l0, fmax(l1, l2));
  const double e0 = exp(l0 - mx), e1 = exp(l1 - mx), e2 = exp(l2 - mx);
  const double se = e0 + e1 + e2;
  const double w0 = e0 / se, w1 = e1 / se, w2 = e2 / se;

  float sp[TT];
  #pragma unroll
  for (int t = 0; t < TT; t++) sp[t] = spk1[((size_t)b * TT + t) * H1C + d];

  double dl[TT];
  #pragma unroll
  for (int t = 0; t < TT; t++) {
    double v = 0.0;
    if (t >= 1) v += (double)sp[t - 1] * w0;
    if (t >= 3) v += (double)sp[t - 3] * w1;
    if (t >= 5) v += (double)sp[t - 5] * w2;
    dl[t] = v;
  }
  double kw[5];
  #pragma unroll
  for (int k = 0; k < 5; k++) kw[k] = (double)dw[d * 5 + k];
  double ys = 0.0;
  #pragma unroll
  for (int t = 0; t < TT; t++) {
    double y = 0.0;
    #pragma unroll
    for (int k = 0; k < 5; k++) {
      const int t2 = t + k - 2;
      if (t2 >= 0 && t2 < TT) y += dl[t2] * kw[k];
    }
    ys += y;
  }
  ysL[d] = ys;
  __syncthreads();
  if (d < CCC) {
    double acc = 0.0;
    for (int dd = 0; dd < H1C; dd++) acc += ysL[dd] * (double)pw[dd * CCC + d];
    out[(size_t)b * CCC + d] = (float)(acc / (double)TT + (double)tb[d]);
  }
}

// ---------------------------------------------------------------------------
extern "C" void kernel_launch(void* const* d_in, const int* in_sizes, int n_in,
                              void* d_out, int out_size, void* d_ws, size_t ws_size,
                              hipStream_t stream)
{
  const float* x      = (const float*)d_in[0];
  const int*   nodes  = (const int*)d_in[1];
  const int*   nbr1   = (const int*)d_in[2];
  const int*   nbr2   = (const int*)d_in[3];
  const float* Ws0    = (const float*)d_in[4];
  const float* Wn0    = (const float*)d_in[5];
  const float* b0     = (const float*)d_in[6];
  const float* Ws1    = (const float*)d_in[7];
  const float* Wn1    = (const float*)d_in[8];
  const float* b1     = (const float*)d_in[9];
  const float* logits = (const float*)d_in[10];
  const float* dw     = (const float*)d_in[11];
  const float* pw     = (const float*)d_in[12];
  const float* tb     = (const float*)d_in[13];
  float* out = (float*)d_out;

  // workspace layout (256B-aligned offsets)
  char* ws = (char*)d_ws;
  unsigned char*  spk0      = (unsigned char*)ws;                 // 23,068,672 B
  float*          spk1      = (float*)(ws + 23068672);            //  4,194,304 B
  unsigned short* Wswz      = (unsigned short*)(ws + 27262976);   //    131,072 B
  float*          WsT       = (float*)(ws + 27394048);            //     65,536 B
  float*          WnT       = (float*)(ws + 27459584);            //     65,536 B
  unsigned int*   band_cnt  = (unsigned int*)(ws + 27525120);     //        256 B
  unsigned int*   band_list = (unsigned int*)(ws + 27525376);
  const long long rem = (long long)ws_size - 27525376LL;
  const int band_cap = rem > 0 ? (int)((rem / 4 < (long long)(1 << 20)) ? rem / 4 : (long long)(1 << 20)) : 0;

  k_prep_w <<<dim3(128),      256, 0, stream>>>(Ws0, Wn0, Wswz, WsT, WnT, band_cnt);
  k_layer0 <<<dim3(176, 16),  256, 0, stream>>>(x, nodes, nbr1, nbr2, Wswz, b0,
                                                spk0, band_list, band_cnt, band_cap);
  k_recheck<<<dim3(2048),     64,  0, stream>>>(x, nodes, nbr1, nbr2, WsT, WnT, b0,
                                                spk0, band_list, band_cnt, band_cap);
  k_layer1 <<<dim3(16, 16),   256, 0, stream>>>(spk0, Ws1, Wn1, b1, spk1);
  k_readout<<<dim3(1024),     64,  0, stream>>>(spk1, logits, dw, pw, tb, out);
}